// Round 11
// baseline (425.323 us; speedup 1.0000x reference)
//
#include <hip/hip_runtime.h>
#include <math.h>

typedef float f32x2 __attribute__((ext_vector_type(2)));
typedef float f32x4 __attribute__((ext_vector_type(4)));
typedef __bf16 bf16x8 __attribute__((ext_vector_type(8)));
typedef unsigned int u32;
typedef u32 u32x4 __attribute__((ext_vector_type(4)));

// bf16 pair (packed in one u32) -> f32x2, 2 VALU ops, no v_cvt.
__device__ __forceinline__ f32x2 bfpair(u32 u) {
  f32x2 r;
  r[0] = __builtin_bit_cast(float, u << 16);
  r[1] = __builtin_bit_cast(float, u & 0xffff0000u);
  return r;
}

// ---------------------------------------------------------------------------
// Phase A: per-atom precompute of layer-1 halves (bf16 in ws) and a
// B-frag-packed copy of W2.
//   U'[a][d] = sum_k X[a][k]*W1[k][d] + b1[d]
//   Y [a][d] = sum_k X[a][k]*W1[64+k][d]
// ---------------------------------------------------------------------------
__global__ __launch_bounds__(256, 2)
void precompute_uy(const float* __restrict__ atom_fea,
                   const float* __restrict__ W1,
                   const float* __restrict__ b1,
                   const float* __restrict__ W2,
                   __bf16* __restrict__ Ub, __bf16* __restrict__ Yb,
                   __bf16* __restrict__ W2pack, int N) {
  const int lane = threadIdx.x & 63;
  const int r16 = lane & 15, g = lane >> 4;
  const int wid = (blockIdx.x * blockDim.x + threadIdx.x) >> 6;
  const int nw = (gridDim.x * blockDim.x) >> 6;

  if (wid == 0) {  // pack W2 into B-frag order (8 KB, once)
#pragma unroll
    for (int ks = 0; ks < 2; ++ks)
#pragma unroll
      for (int c = 0; c < 4; ++c) {
        bf16x8 t;
#pragma unroll
        for (int jj = 0; jj < 8; ++jj)
          t[jj] = (__bf16)W2[(size_t)(32 * ks + 8 * g + jj) * 64 + 16 * c + r16];
        *(bf16x8*)(W2pack + ((size_t)(ks * 4 + c) * 64 + lane) * 8) = t;
      }
  }

  bf16x8 wt[2][4], wb[2][4];
#pragma unroll
  for (int ks = 0; ks < 2; ++ks)
#pragma unroll
    for (int c = 0; c < 4; ++c) {
      bf16x8 t, b;
#pragma unroll
      for (int jj = 0; jj < 8; ++jj) {
        int k = 32 * ks + 8 * g + jj;
        t[jj] = (__bf16)W1[(size_t)k * 64 + 16 * c + r16];
        b[jj] = (__bf16)W1[(size_t)(64 + k) * 64 + 16 * c + r16];
      }
      wt[ks][c] = t; wb[ks][c] = b;
    }
  float b1c[4];
#pragma unroll
  for (int c = 0; c < 4; ++c) b1c[c] = b1[16 * c + r16];

  const int nTiles = (N + 15) >> 4;
  for (int tile = wid; tile < nTiles; tile += nw) {
    const int a0 = tile * 16;
    int arow = a0 + r16; if (arow >= N) arow = N - 1;

    bf16x8 af[2];
#pragma unroll
    for (int ks = 0; ks < 2; ++ks) {
      const float* p = atom_fea + (size_t)arow * 64 + 32 * ks + 8 * g;
      f32x4 x0 = *(const f32x4*)p;
      f32x4 x1 = *(const f32x4*)(p + 4);
      bf16x8 a;
#pragma unroll
      for (int jj = 0; jj < 4; ++jj) { a[jj] = (__bf16)x0[jj]; a[4 + jj] = (__bf16)x1[jj]; }
      af[ks] = a;
    }

    f32x4 uacc[4], yacc[4];
#pragma unroll
    for (int c = 0; c < 4; ++c) { uacc[c] = (f32x4)0.0f; yacc[c] = (f32x4)0.0f; }
#pragma unroll
    for (int ks = 0; ks < 2; ++ks)
#pragma unroll
      for (int c = 0; c < 4; ++c) {
        uacc[c] = __builtin_amdgcn_mfma_f32_16x16x32_bf16(af[ks], wt[ks][c], uacc[c], 0, 0, 0);
        yacc[c] = __builtin_amdgcn_mfma_f32_16x16x32_bf16(af[ks], wb[ks][c], yacc[c], 0, 0, 0);
      }

#pragma unroll
    for (int c = 0; c < 4; ++c)
#pragma unroll
      for (int j = 0; j < 4; ++j) {
        int row = a0 + 4 * g + j;
        if (row < N) {
          Ub[(size_t)row * 64 + 16 * c + r16] = (__bf16)(uacc[c][j] + b1c[c]);
          Yb[(size_t)row * 64 + 16 * c + r16] = (__bf16)yacc[c][j];
        }
      }
  }
}

// ---------------------------------------------------------------------------
// Edge pass: one wave per 16-edge WINDOW (window t = edges [16t,16t+16)).
// self_idx is sorted => windows contain contiguous runs. Per window:
//   H_e = leaky(U'[self_e]+Y[nbr_e]); w_e = atom_w[nbr_e]*exp(H.wg2+bgp)
//   segment-masked suffix fold over r16 -> run head lanes hold sum(wH),
//   sum(w) -> 16 atomicAdd f32 to znum[s][:] + 1 to denom[s] (g==0).
// No per-segment serial chain. Window addresses are pure functions of t,
// so a 2-deep prefetch pipeline fully covers the gather latency.
// ---------------------------------------------------------------------------
__global__ __launch_bounds__(64, 3)
void edge_pass(const float* __restrict__ atom_w,
               const int* __restrict__ self_idx,
               const int* __restrict__ nbr_idx,
               const float* __restrict__ W2,
               const float* __restrict__ b2,
               const float* __restrict__ Wg,
               const float* __restrict__ bg,
               const __bf16* __restrict__ Ub,
               const __bf16* __restrict__ Yb,
               float* __restrict__ znum,
               float* __restrict__ denom, int M) {
  const int lane = threadIdx.x & 63;
  const int r16 = lane & 15, g = lane >> 4;
  const int stride = gridDim.x;
  const int nWin = (M + 15) >> 4;

  // wg2[k] = sum_d W2[k][d]*Wg[d], distributed to this lane's dim slots.
  float wgl = 0.f;
  {
    const float* w2row = W2 + (size_t)lane * 64;
#pragma unroll
    for (int d = 0; d < 64; ++d) wgl = fmaf(w2row[d], Wg[d], wgl);
  }
  f32x2 wg2p[8];
#pragma unroll
  for (int pI = 0; pI < 8; ++pI) {
    const int ks = pI >> 2, jj = (pI & 3) * 2;
    f32x2 t;
    t[0] = __shfl(wgl, 32 * ks + 8 * g + jj);
    t[1] = __shfl(wgl, 32 * ks + 8 * g + jj + 1);
    wg2p[pI] = t;
  }
  float tb = b2[lane] * Wg[lane];
#pragma unroll
  for (int off = 1; off < 64; off <<= 1) tb += __shfl_xor(tb, off);
  const float bgp = bg[0] + tb;

  int t = blockIdx.x;
  if (t >= nWin) return;

  // ---- pipeline state ----
  int sidc; float awc; u32x4 yc0, yc1, uc0, uc1;   // current (data ready)
  int sidn = -1, nbn = 0;                          // next window ids (ready)
  int sidi = -1, nbi = 0;                          // next-next ids (in flight)
  u32x4 yn0 = {}, yn1 = {}, un0 = {}, un1 = {}; float awn = 0.f;

  {  // prologue: window t fully; ids for t+stride
    const int e = 16 * t + r16;
    sidc = (e < M) ? self_idx[e] : -1;
    const int nb = (e < M) ? nbr_idx[e] : 0;
    const int sx = (sidc < 0) ? 0 : sidc;
    yc0 = *(const u32x4*)(Yb + ((size_t)nb << 6) + 8 * g);
    yc1 = *(const u32x4*)(Yb + ((size_t)nb << 6) + 32 + 8 * g);
    uc0 = *(const u32x4*)(Ub + ((size_t)sx << 6) + 8 * g);
    uc1 = *(const u32x4*)(Ub + ((size_t)sx << 6) + 32 + 8 * g);
    awc = atom_w[nb];
  }
  if (t + stride < nWin) {
    const int e = 16 * (t + stride) + r16;
    sidn = (e < M) ? self_idx[e] : -1;
    nbn = (e < M) ? nbr_idx[e] : 0;
  }

  for (; t < nWin; t += stride) {
    const int t1 = t + stride, t2 = t + 2 * stride;

    // (1) ids for t+2*stride (pure function of t2)
    if (t2 < nWin) {
      const int e = 16 * t2 + r16;
      sidi = (e < M) ? self_idx[e] : -1;
      nbi = (e < M) ? nbr_idx[e] : 0;
    }
    // (2) gathers for t+stride (ids arrived last iteration)
    if (t1 < nWin) {
      const int sx = (sidn < 0) ? 0 : sidn;
      yn0 = *(const u32x4*)(Yb + ((size_t)nbn << 6) + 8 * g);
      yn1 = *(const u32x4*)(Yb + ((size_t)nbn << 6) + 32 + 8 * g);
      un0 = *(const u32x4*)(Ub + ((size_t)sx << 6) + 8 * g);
      un1 = *(const u32x4*)(Ub + ((size_t)sx << 6) + 32 + 8 * g);
      awn = atom_w[nbn];
    }

    // (3) compute window t
    const bool vc = sidc >= 0;
    f32x2 h[8];
    f32x2 d2 = (f32x2)0.0f;
#pragma unroll
    for (int q = 0; q < 4; ++q) {
      f32x2 a = bfpair(uc0[q]) + bfpair(yc0[q]);
      f32x2 b = bfpair(uc1[q]) + bfpair(yc1[q]);
      f32x2 ha, hb;
      ha[0] = fmaxf(a[0], 0.01f * a[0]); ha[1] = fmaxf(a[1], 0.01f * a[1]);
      hb[0] = fmaxf(b[0], 0.01f * b[0]); hb[1] = fmaxf(b[1], 0.01f * b[1]);
      h[q] = ha; h[4 + q] = hb;
      d2 += ha * wg2p[q];
      d2 += hb * wg2p[4 + q];
    }
    float p = d2[0] + d2[1];
    p += __shfl_xor(p, 16);
    p += __shfl_xor(p, 32);
    const float w = vc ? awc * __expf(p + bgp) : 0.f;
    const f32x2 wv = {w, w};
#pragma unroll
    for (int k = 0; k < 8; ++k) h[k] *= wv;     // h := w*H

    // segment-masked suffix fold over r16 (sorted => runs contiguous)
    const int sidm = sidc;
    float wacc = w;
#pragma unroll
    for (int kk = 1; kk <= 8; kk <<= 1) {
      const int sd = __shfl_down(sidm, kk);
      const bool pr = (r16 + kk < 16) && (sd == sidm);
      const float tw = __shfl_down(wacc, kk);
      wacc += pr ? tw : 0.f;
#pragma unroll
      for (int j = 0; j < 8; ++j) {
        f32x2 th;
        th[0] = __shfl_down(h[j][0], kk);
        th[1] = __shfl_down(h[j][1], kk);
        h[j] += pr ? th : (f32x2)0.0f;
      }
    }
    const int su = __shfl_up(sidm, 1);
    const bool head = (r16 == 0) || (su != sidm);

    if (head && vc) {
      float* zp = znum + ((size_t)sidm << 6);
#pragma unroll
      for (int q = 0; q < 4; ++q) {
        atomicAdd(zp + 8 * g + 2 * q,          h[q][0]);
        atomicAdd(zp + 8 * g + 2 * q + 1,      h[q][1]);
        atomicAdd(zp + 32 + 8 * g + 2 * q,     h[4 + q][0]);
        atomicAdd(zp + 32 + 8 * g + 2 * q + 1, h[4 + q][1]);
      }
      if (g == 0) atomicAdd(denom + sidm, wacc);
    }

    // (4) rotate
    sidc = sidn; awc = awn;
    yc0 = yn0; yc1 = yn1; uc0 = un0; uc1 = un1;
    sidn = sidi; nbn = nbi;
  }
}

// ---------------------------------------------------------------------------
// Finalize: dense atom-parallel MFMA pass.
//   out[s] = (znum[s]@W2 + denom[s]*b2) / (denom[s]+1e-13) + atom_fea[s]
// ---------------------------------------------------------------------------
__global__ __launch_bounds__(256, 2)
void finalize(const float* __restrict__ atom_fea,
              const float* __restrict__ b2,
              const __bf16* __restrict__ W2pack,
              const float* __restrict__ znum,
              const float* __restrict__ denom,
              float* __restrict__ out, int N) {
  const int lane = threadIdx.x & 63;
  const int r16 = lane & 15, g = lane >> 4;
  const int wid = (blockIdx.x * blockDim.x + threadIdx.x) >> 6;
  const int nw = (gridDim.x * blockDim.x) >> 6;

  float b2c[4];
#pragma unroll
  for (int c = 0; c < 4; ++c) b2c[c] = b2[16 * c + r16];

  bf16x8 wf[2][4];
#pragma unroll
  for (int ks = 0; ks < 2; ++ks)
#pragma unroll
    for (int c = 0; c < 4; ++c)
      wf[ks][c] = *(const bf16x8*)(W2pack + ((size_t)(ks * 4 + c) * 64 + lane) * 8);

  const int nTiles = (N + 15) >> 4;
  for (int tile = wid; tile < nTiles; tile += nw) {
    const int a0 = tile * 16;
    int arow = a0 + r16; if (arow >= N) arow = N - 1;

    const float* zr = znum + ((size_t)arow << 6);
    f32x4 z00 = *(const f32x4*)(zr + 8 * g);
    f32x4 z01 = *(const f32x4*)(zr + 8 * g + 4);
    f32x4 z10 = *(const f32x4*)(zr + 32 + 8 * g);
    f32x4 z11 = *(const f32x4*)(zr + 32 + 8 * g + 4);
    bf16x8 za, zb;
#pragma unroll
    for (int j = 0; j < 4; ++j) {
      za[j] = (__bf16)z00[j]; za[4 + j] = (__bf16)z01[j];
      zb[j] = (__bf16)z10[j]; zb[4 + j] = (__bf16)z11[j];
    }

    f32x4 facc[4];
#pragma unroll
    for (int c = 0; c < 4; ++c) facc[c] = (f32x4)0.0f;
#pragma unroll
    for (int c = 0; c < 4; ++c) {
      facc[c] = __builtin_amdgcn_mfma_f32_16x16x32_bf16(za, wf[0][c], facc[c], 0, 0, 0);
      facc[c] = __builtin_amdgcn_mfma_f32_16x16x32_bf16(zb, wf[1][c], facc[c], 0, 0, 0);
    }

#pragma unroll
    for (int c = 0; c < 4; ++c)
#pragma unroll
      for (int j = 0; j < 4; ++j) {
        const int row = a0 + 4 * g + j;
        if (row < N) {
          const float dd = denom[row];
          const float val = (facc[c][j] + dd * b2c[c]) / (dd + 1e-13f)
                          + atom_fea[(size_t)row * 64 + 16 * c + r16];
          out[(size_t)row * 64 + 16 * c + r16] = val;
        }
      }
  }
}

extern "C" void kernel_launch(void* const* d_in, const int* in_sizes, int n_in,
                              void* d_out, int out_size, void* d_ws, size_t ws_size,
                              hipStream_t stream) {
  const float* atom_w   = (const float*)d_in[0];
  const float* atom_fea = (const float*)d_in[1];
  const int*   self_idx = (const int*)d_in[2];
  const int*   nbr_idx  = (const int*)d_in[3];
  const float* W1 = (const float*)d_in[4];
  const float* b1 = (const float*)d_in[5];
  const float* W2 = (const float*)d_in[6];
  const float* b2 = (const float*)d_in[7];
  const float* Wg = (const float*)d_in[8];
  const float* bg = (const float*)d_in[9];
  float* out = (float*)d_out;

  const int N = in_sizes[0];   // atom_weights is (N,1)
  const int M = in_sizes[2];   // self_fea_idx is (M,)

  char* ws = (char*)d_ws;
  __bf16* W2pack = (__bf16*)ws;                       // 8 KB
  __bf16* Ub = W2pack + 8 * 64 * 8;                   // N*64 bf16
  __bf16* Yb = Ub + (size_t)N * 64;                   // N*64 bf16
  float* znum = (float*)(Yb + (size_t)N * 64);        // N*64 f32
  float* denom = znum + (size_t)N * 64;               // N f32

  // zero the atomic accumulators every call (znum+denom contiguous)
  hipMemsetAsync(znum, 0, (size_t)N * 65 * sizeof(float), stream);

  hipLaunchKernelGGL(precompute_uy, dim3(512), dim3(256), 0, stream,
                     atom_fea, W1, b1, W2, Ub, Yb, W2pack, N);
  hipLaunchKernelGGL(edge_pass, dim3(8192), dim3(64), 0, stream,
                     atom_w, self_idx, nbr_idx, W2, b2, Wg, bg,
                     Ub, Yb, znum, denom, M);
  hipLaunchKernelGGL(finalize, dim3(512), dim3(256), 0, stream,
                     atom_fea, b2, W2pack, znum, denom, out, N);
}

// Round 12
// 101.045 us; speedup vs baseline: 4.2092x; 4.2092x over previous
//
#include <hip/hip_runtime.h>
#include <math.h>

typedef float f32x2 __attribute__((ext_vector_type(2)));
typedef float f32x4 __attribute__((ext_vector_type(4)));
typedef __bf16 bf16x8 __attribute__((ext_vector_type(8)));
typedef unsigned int u32;
typedef u32 u32x4 __attribute__((ext_vector_type(4)));

// bf16 pair (packed in one u32) -> f32x2; 2 bit-ops, no v_cvt.
__device__ __forceinline__ f32x2 bfpair(u32 u) {
  f32x2 r;
  r[0] = __builtin_bit_cast(float, u << 16);
  r[1] = __builtin_bit_cast(float, u & 0xffff0000u);
  return r;
}

// ---------------------------------------------------------------------------
// Setup (fused): CSR row offsets + W2 B-frag pack + per-atom layer-1 halves.
//   row_start[j] = first edge with segment id >= j; row_start[N] = M
//   U'[a][d] = sum_k X[a][k]*W1[k][d] + b1[d]   (bf16)
//   Y [a][d] = sum_k X[a][k]*W1[64+k][d]        (bf16)
//   W2pack[(ks*4+c)*64 + lane][0..7] = W2[32ks+8g+j][16c+r16]
// ---------------------------------------------------------------------------
__global__ __launch_bounds__(256, 2)
void setup_all(const float* __restrict__ atom_fea,
               const float* __restrict__ W1,
               const float* __restrict__ b1,
               const float* __restrict__ W2,
               const int* __restrict__ self_idx,
               int* __restrict__ row_start,
               __bf16* __restrict__ Ub, __bf16* __restrict__ Yb,
               __bf16* __restrict__ W2pack, int M, int N) {
  const int lane = threadIdx.x & 63;
  const int r16 = lane & 15, g = lane >> 4;
  const int tidg = blockIdx.x * blockDim.x + threadIdx.x;
  const int tot = gridDim.x * blockDim.x;
  const int wid = tidg >> 6;
  const int nw = tot >> 6;

  // ---- part 1: CSR row offsets (grid-stride over edges) ----
  for (int i = tidg; i < M; i += tot) {
    const int cur = self_idx[i];
    const int prev = (i == 0) ? -1 : self_idx[i - 1];
    for (int j = prev + 1; j <= cur; ++j) row_start[j] = i;
    if (i == M - 1) {
      for (int j = cur + 1; j <= N; ++j) row_start[j] = M;
    }
  }

  // ---- part 2: W2 B-frag pack (one wave) ----
  if (wid == 0) {
#pragma unroll
    for (int ks = 0; ks < 2; ++ks)
#pragma unroll
      for (int c = 0; c < 4; ++c) {
        bf16x8 t;
#pragma unroll
        for (int jj = 0; jj < 8; ++jj)
          t[jj] = (__bf16)W2[(size_t)(32 * ks + 8 * g + jj) * 64 + 16 * c + r16];
        *(bf16x8*)(W2pack + ((size_t)(ks * 4 + c) * 64 + lane) * 8) = t;
      }
  }

  // ---- part 3: U'/Y via MFMA (one wave per 16-atom tile) ----
  bf16x8 wt[2][4], wb[2][4];
#pragma unroll
  for (int ks = 0; ks < 2; ++ks)
#pragma unroll
    for (int c = 0; c < 4; ++c) {
      bf16x8 t, b;
#pragma unroll
      for (int jj = 0; jj < 8; ++jj) {
        int k = 32 * ks + 8 * g + jj;
        t[jj] = (__bf16)W1[(size_t)k * 64 + 16 * c + r16];
        b[jj] = (__bf16)W1[(size_t)(64 + k) * 64 + 16 * c + r16];
      }
      wt[ks][c] = t; wb[ks][c] = b;
    }
  float b1c[4];
#pragma unroll
  for (int c = 0; c < 4; ++c) b1c[c] = b1[16 * c + r16];

  const int nTiles = (N + 15) >> 4;
  for (int tile = wid; tile < nTiles; tile += nw) {
    const int a0 = tile * 16;
    int arow = a0 + r16; if (arow >= N) arow = N - 1;

    bf16x8 af[2];
#pragma unroll
    for (int ks = 0; ks < 2; ++ks) {
      const float* p = atom_fea + (size_t)arow * 64 + 32 * ks + 8 * g;
      f32x4 x0 = *(const f32x4*)p;
      f32x4 x1 = *(const f32x4*)(p + 4);
      bf16x8 a;
#pragma unroll
      for (int jj = 0; jj < 4; ++jj) { a[jj] = (__bf16)x0[jj]; a[4 + jj] = (__bf16)x1[jj]; }
      af[ks] = a;
    }

    f32x4 uacc[4], yacc[4];
#pragma unroll
    for (int c = 0; c < 4; ++c) { uacc[c] = (f32x4)0.0f; yacc[c] = (f32x4)0.0f; }
#pragma unroll
    for (int ks = 0; ks < 2; ++ks)
#pragma unroll
      for (int c = 0; c < 4; ++c) {
        uacc[c] = __builtin_amdgcn_mfma_f32_16x16x32_bf16(af[ks], wt[ks][c], uacc[c], 0, 0, 0);
        yacc[c] = __builtin_amdgcn_mfma_f32_16x16x32_bf16(af[ks], wb[ks][c], yacc[c], 0, 0, 0);
      }

#pragma unroll
    for (int c = 0; c < 4; ++c)
#pragma unroll
      for (int j = 0; j < 4; ++j) {
        int row = a0 + 4 * g + j;
        if (row < N) {
          Ub[(size_t)row * 64 + 16 * c + r16] = (__bf16)(uacc[c][j] + b1c[c]);
          Yb[(size_t)row * 64 + 16 * c + r16] = (__bf16)yacc[c][j];
        }
      }
  }
}

// ---------------------------------------------------------------------------
// Main fused kernel: EXACT R5 structure (best measured: 96 us, VGPR 64,
// zero spill) with the per-tile math on packed f32x2 (v_pk_* + bfpair
// bit-ops) -- ~40% fewer VALU instructions per tile.
//   pooled = (sum_e w_e H_e) @ W2 + (sum_e w_e) b2
//   w_e = atom_w[nbr_e]*exp(H_e.wg2 + bgp),  wg2 = W2@Wg, bgp = bg + b2.Wg
// One wave per segment (grid-stride); rotating prefetch of next segment's
// head (row_start pair + U' row); per-segment finalize = 8 MFMA vs W2pack.
// ---------------------------------------------------------------------------
__global__ __launch_bounds__(64, 4)
void fused_pool(const float* __restrict__ atom_w,
                const float* __restrict__ atom_fea,
                const int* __restrict__ nbr_idx,
                const float* __restrict__ W2,
                const float* __restrict__ b2,
                const float* __restrict__ Wg,
                const float* __restrict__ bg,
                const int* __restrict__ row_start,
                const __bf16* __restrict__ Ub,
                const __bf16* __restrict__ Yb,
                const __bf16* __restrict__ W2pack,
                float* __restrict__ out, int N) {
  const int lane = threadIdx.x & 63;
  const int r16 = lane & 15, g = lane >> 4;
  const int wid = blockIdx.x;
  const int nw = gridDim.x;

  // wg2[k] = sum_d W2[k][d]*Wg[d]  (lane holds k = lane)
  float wgl = 0.f;
  {
    const float* w2row = W2 + (size_t)lane * 64;
#pragma unroll
    for (int d = 0; d < 64; ++d) wgl = fmaf(w2row[d], Wg[d], wgl);
  }
  // distribute wg2 into this lane's A-frag k-slot pairs (k = 32ks+8g+jj)
  f32x2 wg2p[8];
#pragma unroll
  for (int pI = 0; pI < 8; ++pI) {
    const int ks = pI >> 2, jj = (pI & 3) * 2;
    f32x2 t;
    t[0] = __shfl(wgl, 32 * ks + 8 * g + jj);
    t[1] = __shfl(wgl, 32 * ks + 8 * g + jj + 1);
    wg2p[pI] = t;
  }

  // bgp = bg + sum_d b2[d]*Wg[d]
  float tb = b2[lane] * Wg[lane];
#pragma unroll
  for (int off = 1; off < 64; off <<= 1) tb += __shfl_xor(tb, off);
  const float bgp = bg[0] + tb;
  const float b2l = b2[lane];

  // rotating prefetch of next segment's CSR range + U' row
  int s = wid;
  int nStart = 0, nEnd = 0;
  u32x4 nu0 = {}, nu1 = {};
  if (s < N) {
    nStart = row_start[s];
    nEnd = row_start[s + 1];
    nu0 = *(const u32x4*)(Ub + (size_t)s * 64 + 8 * g);
    nu1 = *(const u32x4*)(Ub + (size_t)s * 64 + 32 + 8 * g);
  }

  for (; s < N; s += nw) {
    const int start = nStart, end = nEnd;
    const u32x4 u0 = nu0, u1 = nu1;
    const float xr = atom_fea[(size_t)s * 64 + lane];  // residual

    const int s2 = s + nw;
    if (s2 < N) {
      nStart = row_start[s2];
      nEnd = row_start[s2 + 1];
      nu0 = *(const u32x4*)(Ub + (size_t)s2 * 64 + 8 * g);
      nu1 = *(const u32x4*)(Ub + (size_t)s2 * 64 + 32 + 8 * g);
    }

    // unpack U' to f32x2 pairs (slot pI: dims (8g+2(pI&3), +1), ks=pI>>2)
    f32x2 uf2[8];
#pragma unroll
    for (int pI = 0; pI < 4; ++pI) {
      uf2[pI] = bfpair(u0[pI]);
      uf2[4 + pI] = bfpair(u1[pI]);
    }

    f32x2 z2[8];
#pragma unroll
    for (int k = 0; k < 8; ++k) z2[k] = (f32x2)0.0f;
    float wsum = 0.f;

    for (int base = start; base < end; base += 16) {
      const int er = base + r16;
      const bool valid = er < end;
      const int nb = valid ? nbr_idx[er] : 0;
      const float aw = atom_w[nb];
      const u32x4 y0 = *(const u32x4*)(Yb + ((size_t)nb << 6) + 8 * g);
      const u32x4 y1 = *(const u32x4*)(Yb + ((size_t)nb << 6) + 32 + 8 * g);

      // H (packed) + gate dot, all on v_pk_* ops
      f32x2 h2[8];
      f32x2 d2 = (f32x2)0.0f;
#pragma unroll
      for (int q = 0; q < 4; ++q) {
        f32x2 a = uf2[q] + bfpair(y0[q]);
        f32x2 b = uf2[4 + q] + bfpair(y1[q]);
        f32x2 ta = a * 0.01f;
        f32x2 tbv = b * 0.01f;
        f32x2 ha, hb;
        ha[0] = fmaxf(a[0], ta[0]); ha[1] = fmaxf(a[1], ta[1]);
        hb[0] = fmaxf(b[0], tbv[0]); hb[1] = fmaxf(b[1], tbv[1]);
        h2[q] = ha; h2[4 + q] = hb;
        d2 += ha * wg2p[q];
        d2 += hb * wg2p[4 + q];
      }
      float p = d2[0] + d2[1];
      p += __shfl_xor(p, 16);
      p += __shfl_xor(p, 32);

      const float w = valid ? aw * __expf(p + bgp) : 0.f;
      wsum += w;
      const f32x2 wv = {w, w};
#pragma unroll
      for (int k = 0; k < 8; ++k) z2[k] += wv * h2[k];
    }

    // ---- segment finalize: pooled = z @ W2 + wsum*b2, then /ssum + x ----
    bf16x8 zf0, zf1;
#pragma unroll
    for (int pI = 0; pI < 4; ++pI) {
      zf0[2 * pI] = (__bf16)z2[pI][0];
      zf0[2 * pI + 1] = (__bf16)z2[pI][1];
      zf1[2 * pI] = (__bf16)z2[4 + pI][0];
      zf1[2 * pI + 1] = (__bf16)z2[4 + pI][1];
    }

    f32x4 facc[4];
#pragma unroll
    for (int c = 0; c < 4; ++c) facc[c] = (f32x4)0.0f;
#pragma unroll
    for (int c = 0; c < 4; ++c) {
      const bf16x8 wf0 = *(const bf16x8*)(W2pack + ((size_t)(0 * 4 + c) * 64 + lane) * 8);
      const bf16x8 wf1 = *(const bf16x8*)(W2pack + ((size_t)(1 * 4 + c) * 64 + lane) * 8);
      facc[c] = __builtin_amdgcn_mfma_f32_16x16x32_bf16(zf0, wf0, facc[c], 0, 0, 0);
      facc[c] = __builtin_amdgcn_mfma_f32_16x16x32_bf16(zf1, wf1, facc[c], 0, 0, 0);
    }

    // sum over the 16 C rows (z partial rows): in-lane + cross-g shfl
    float accv[4];
#pragma unroll
    for (int c = 0; c < 4; ++c) {
      float a = (facc[c][0] + facc[c][1]) + (facc[c][2] + facc[c][3]);
      a += __shfl_xor(a, 16);
      a += __shfl_xor(a, 32);
      accv[c] = a;   // = pooled_num[16c + r16] (pre-b2)
    }

    // ssum = sum over r16 groups of per-lane wsum
    float ssum = wsum;
    ssum += __shfl_xor(ssum, 1);
    ssum += __shfl_xor(ssum, 2);
    ssum += __shfl_xor(ssum, 4);
    ssum += __shfl_xor(ssum, 8);

    // lane's output dim d = lane = 16g + r16 -> chunk c = g
    float val = accv[0];
    val = (g == 1) ? accv[1] : val;
    val = (g == 2) ? accv[2] : val;
    val = (g == 3) ? accv[3] : val;
    val = fmaf(ssum, b2l, val);

    out[(size_t)s * 64 + lane] = val / (ssum + 1e-13f) + xr;
  }
}

extern "C" void kernel_launch(void* const* d_in, const int* in_sizes, int n_in,
                              void* d_out, int out_size, void* d_ws, size_t ws_size,
                              hipStream_t stream) {
  const float* atom_w   = (const float*)d_in[0];
  const float* atom_fea = (const float*)d_in[1];
  const int*   self_idx = (const int*)d_in[2];
  const int*   nbr_idx  = (const int*)d_in[3];
  const float* W1 = (const float*)d_in[4];
  const float* b1 = (const float*)d_in[5];
  const float* W2 = (const float*)d_in[6];
  const float* b2 = (const float*)d_in[7];
  const float* Wg = (const float*)d_in[8];
  const float* bg = (const float*)d_in[9];
  float* out = (float*)d_out;

  const int N = in_sizes[0];   // atom_weights is (N,1)
  const int M = in_sizes[2];   // self_fea_idx is (M,)

  char* ws = (char*)d_ws;
  int* row_start = (int*)ws;
  size_t off = ((size_t)(N + 1) * sizeof(int) + 255) & ~(size_t)255;
  __bf16* W2pack = (__bf16*)(ws + off);
  __bf16* Ub = W2pack + 8 * 64 * 8;          // 8 KB pack region
  __bf16* Yb = Ub + (size_t)N * 64;

  hipLaunchKernelGGL(setup_all, dim3(512), dim3(256), 0, stream,
                     atom_fea, W1, b1, W2, self_idx, row_start,
                     Ub, Yb, W2pack, M, N);
  hipLaunchKernelGGL(fused_pool, dim3(8192), dim3(64), 0, stream,
                     atom_w, atom_fea, nbr_idx, W2, b2, Wg, bg,
                     row_start, Ub, Yb, W2pack, out, N);
}